// Round 12
// baseline (315.024 us; speedup 1.0000x reference)
//
#include <hip/hip_runtime.h>
#include <hip/hip_bf16.h>
#include <cstdint>
#include <cstddef>

#define M_DIM 8192
#define K_DIM 4096
#define N_DIM 4096

typedef __bf16 bf16x8 __attribute__((ext_vector_type(8)));
typedef float  f32x4  __attribute__((ext_vector_type(4)));

__device__ __forceinline__ unsigned short f32_to_bf16_rne(float f) {
  unsigned int u = __builtin_bit_cast(unsigned int, f);
  u += 0x7FFFu + ((u >> 16) & 1u);
  return (unsigned short)(u >> 16);
}

// Single fused fp32->bf16 conversion for both A and W (one launch).
__global__ void __launch_bounds__(256) cvt_both(const float* __restrict__ A,
                                                const float* __restrict__ W,
                                                unsigned short* __restrict__ Abf,
                                                unsigned short* __restrict__ Wbf,
                                                int a4, int tot4) {
  int i = blockIdx.x * blockDim.x + threadIdx.x;
  int stride = gridDim.x * blockDim.x;
  for (; i < tot4; i += stride) {
    const float4* s = (i < a4) ? &reinterpret_cast<const float4*>(A)[i]
                               : &reinterpret_cast<const float4*>(W)[i - a4];
    ushort4* d = (i < a4) ? &reinterpret_cast<ushort4*>(Abf)[i]
                          : &reinterpret_cast<ushort4*>(Wbf)[i - a4];
    float4 v = *s;
    ushort4 o;
    o.x = f32_to_bf16_rne(v.x);
    o.y = f32_to_bf16_rne(v.y);
    o.z = f32_to_bf16_rne(v.z);
    o.w = f32_to_bf16_rne(v.w);
    *d = o;
  }
}

__device__ __forceinline__ void gload16(const void* g, void* l) {
  __builtin_amdgcn_global_load_lds((const __attribute__((address_space(1))) void*)g,
                                   (__attribute__((address_space(3))) void*)l, 16, 0, 0);
}

// 128x128-tile, BK=64, 4-wave (2Mx2N), 1-window-per-K-tile GEMM, 2 blocks/CU.
//
// ROUND-12 RATIONALE (r11 re-anchored r7 at 216us/59.3% MfmaUtil): r7's
// residual stall is lockstep fill/drain + 3x LDS read amplification that a
// single resident block can't hide. This kernel trades tile size for
// CO-RESIDENCY at a register budget that FITS (r8's failure was spills from
// keeping acc=128 while demanding 4 waves/SIMD; here acc=64):
//   - 64 KiB LDS (2buf x (A 16K + B 16K)) -> 2 blocks/CU (160/64).
//   - 4 waves x 64x64 wave-tile -> acc = 4x4 f32x4 = 64 AGPR; ~150 VGPR tot.
//   - LDS read amplification 2x (A,B each shared by 2 waves): 64 KB/K-tile
//     vs r7's 192 KB per 256^2 tile (1.5x less global LDS read traffic).
//   - One window per K-tile: 64 barriers total (r7: 128).
// Schedule window k (bb=k&1): { STAGE(tile k+1 -> bb^1) [8 gload16];
//   16 ds_read_b128; 32 MFMA (T19-interleaved, T5 setprio); VM(0); BAR }.
//   WAR: stage targets buf bb^1, last read in window k-1; every read there
//     feeds a same-window MFMA whose counted lgkmcnt wait precedes the
//     window k-1 barrier -> reads complete before any wave crosses it ->
//     stage (issued after) is safe.
//   Visibility: per-wave VM(0) then BAR at end of window k -> tile k+1
//     fully landed before window k+1 reads. VM(0) is 1-window (~900cy)
//     after issue; the co-resident block hides residual drain (m97
//     mechanism).
// T2 swizzle identical algebra to r7: LDS 16B-chunk (row,j) holds global
// k-chunk j ^ (row&7); staged via pre-swizzled global source + linear
// wave-uniform gload_lds dest; ds_read applies the XOR (row&7 == fr&7 ->
// per-thread-constant low bits). 0 bank conflicts expected (same pattern
// as r7's measured 0).
__global__ void __launch_bounds__(256, 2)
gemm128_2b(const __bf16* __restrict__ A, const __bf16* __restrict__ W,
           const float* __restrict__ bias, float* __restrict__ out) {
  __shared__ __align__(16) char lds[65536];

  const int tid  = threadIdx.x;
  const int wave = tid >> 6, lane = tid & 63;
  const int wm = wave >> 1, wn = wave & 1;   // 2 x 2 wave grid, each owns 64x64
  const int fr = lane & 15, ko = lane >> 4;

  // 2D XCD grouping (bijective, 2048 blocks, 8 XCDs): group g owns bm in
  // [(g&3)*16,+16), bn in [(g>>2)*16,+16); per-K-step active set ~512 KB/L2.
  const int swzid = ((blockIdx.x & 7) << 8) + (blockIdx.x >> 3);
  const int g = swzid >> 8, w = swzid & 255;
  const int bm = ((g & 3) << 4) + (w & 15);
  const int bn = ((g >> 2) << 4) + (w >> 4);
  const int brow = bm << 7, bcol = bn << 7;

  // Staging: operand tile = 128 rows x 64 k (16 KiB) = 1024 chunks; 256
  // threads x 4 gload16 each (rows r0 + 32j). col (t&7) and row&7 invariant
  // across j (32j % 8 == 0) -> one pre-swizzled source base per operand.
  const int r0 = tid >> 3;
  const int jc = (((tid & 7) ^ (r0 & 7)) << 4);
  const char* aSrc = (const char*)A + (size_t)(brow + r0) * (K_DIM * 2) + jc;
  const char* bSrc = (const char*)W + (size_t)(bcol + r0) * (K_DIM * 2) + jc;
  char* dstW = lds + (wave << 10);  // wave-uniform LDS base (lane*16 added by HW)

  // STAGE(bb, kt): tile kt (A+B) -> buf bb. 8 gload16, 4 KiB strides.
#define STAGE(bb, kt) do {                                                     \
    const char* sa_ = aSrc + (size_t)(kt) * 128;                               \
    const char* sb_ = bSrc + (size_t)(kt) * 128;                               \
    char* da_ = dstW + (bb) * 32768;                                           \
    char* db_ = da_ + 16384;                                                   \
    gload16(sa_,                      da_);                                    \
    gload16(sa_ + 32ull * K_DIM * 2,  da_ + 4096);                             \
    gload16(sa_ + 64ull * K_DIM * 2,  da_ + 8192);                             \
    gload16(sa_ + 96ull * K_DIM * 2,  da_ + 12288);                            \
    gload16(sb_,                      db_);                                    \
    gload16(sb_ + 32ull * K_DIM * 2,  db_ + 4096);                             \
    gload16(sb_ + 64ull * K_DIM * 2,  db_ + 8192);                             \
    gload16(sb_ + 96ull * K_DIM * 2,  db_ + 12288);                            \
  } while (0)

  // Hoisted ds_read bases: row = (wm|wn)*64 + f*16 + fr, row&7 == fr&7;
  // byte = row*128 + ((k2*64 + ko*16) ^ ((fr&7)*16)). Frag select f -> +2048.
  const int low0 = (ko << 4) ^ ((fr & 7) << 4);
  const int low1 = low0 ^ 64;
  const char* baA[2][2];  // [bb][k2] -- constant-indexed only
  const char* baB[2][2];
  baA[0][0] = lds + (wm << 13) + (fr << 7) + low0;
  baA[0][1] = lds + (wm << 13) + (fr << 7) + low1;
  baA[1][0] = baA[0][0] + 32768;
  baA[1][1] = baA[0][1] + 32768;
  baB[0][0] = lds + 16384 + (wn << 13) + (fr << 7) + low0;
  baB[0][1] = lds + 16384 + (wn << 13) + (fr << 7) + low1;
  baB[1][0] = baB[0][0] + 32768;
  baB[1][1] = baB[0][1] + 32768;

  bf16x8 a[4][2];   // 4 m-frags x 2 k-steps
  bf16x8 b[4][2];   // 4 n-frags x 2 k-steps
  f32x4 acc[4][4] = {};

  // Read order: b0,b1 | a0..a3 | b2,b3 -- each T19 group dependency-ready.
#define LDALL(bb) do {                                                         \
    b[0][0] = *(const bf16x8*)(baB[bb][0]);                                    \
    b[0][1] = *(const bf16x8*)(baB[bb][1]);                                    \
    b[1][0] = *(const bf16x8*)(baB[bb][0] + 2048);                             \
    b[1][1] = *(const bf16x8*)(baB[bb][1] + 2048);                             \
    _Pragma("unroll") for (int ml = 0; ml < 4; ++ml) {                         \
      a[ml][0] = *(const bf16x8*)(baA[bb][0] + (ml << 11));                    \
      a[ml][1] = *(const bf16x8*)(baA[bb][1] + (ml << 11)); }                  \
    b[2][0] = *(const bf16x8*)(baB[bb][0] + 4096);                             \
    b[2][1] = *(const bf16x8*)(baB[bb][1] + 4096);                             \
    b[3][0] = *(const bf16x8*)(baB[bb][0] + 6144);                             \
    b[3][1] = *(const bf16x8*)(baB[bb][1] + 6144);                             \
  } while (0)

#define MFMA_N01() do {                                                        \
    _Pragma("unroll") for (int ml = 0; ml < 4; ++ml)                           \
    _Pragma("unroll") for (int nl = 0; nl < 2; ++nl)                           \
    _Pragma("unroll") for (int k2 = 0; k2 < 2; ++k2)                           \
      acc[ml][nl] = __builtin_amdgcn_mfma_f32_16x16x32_bf16(                   \
          a[ml][k2], b[nl][k2], acc[ml][nl], 0, 0, 0);                         \
  } while (0)
#define MFMA_N23() do {                                                        \
    _Pragma("unroll") for (int ml = 0; ml < 4; ++ml)                           \
    _Pragma("unroll") for (int nl = 2; nl < 4; ++nl)                           \
    _Pragma("unroll") for (int k2 = 0; k2 < 2; ++k2)                           \
      acc[ml][nl] = __builtin_amdgcn_mfma_f32_16x16x32_bf16(                   \
          a[ml][k2], b[nl][k2], acc[ml][nl], 0, 0, 0);                         \
  } while (0)

#define BAR() __builtin_amdgcn_s_barrier()
#define VM0() asm volatile("s_waitcnt vmcnt(0)" ::: "memory")
#define SP1() __builtin_amdgcn_s_setprio(1)
#define SP0() __builtin_amdgcn_s_setprio(0)
#define SGB(m, n) __builtin_amdgcn_sched_group_barrier((m), (n), 0)

  // T19 interleave: 16 DSR, 32 MFMA, 8 VMEM per window.
  // {b0,b1,a0}=6r -> 4 MFMA; a1,a2,a3 -> 4 each; b2 -> 8; b3 -> 8.
#define ILV() do {                                                             \
    SGB(0x10, 4);                                                              \
    SGB(0x100, 6); SGB(0x8, 4);                                                \
    SGB(0x100, 2); SGB(0x8, 4);                                                \
    SGB(0x10, 4);                                                              \
    SGB(0x100, 2); SGB(0x8, 4);                                                \
    SGB(0x100, 2); SGB(0x8, 4);                                                \
    SGB(0x100, 2); SGB(0x8, 8);                                                \
    SGB(0x100, 2); SGB(0x8, 8);                                                \
  } while (0)

  // Prologue: tile 0 -> buf0.
  STAGE(0, 0);
  VM0();
  BAR();

  for (int i = 0; i < 31; ++i) {
    const int k = 2 * i;
    // window k (buf0): stage k+1 -> buf1
    SP1();
    STAGE(1, k + 1);
    LDALL(0);
    MFMA_N01(); MFMA_N23();
    ILV();
    SP0(); VM0(); BAR();
    // window k+1 (buf1): stage k+2 -> buf0
    SP1();
    STAGE(0, k + 2);
    LDALL(1);
    MFMA_N01(); MFMA_N23();
    ILV();
    SP0(); VM0(); BAR();
  }
  // Window 62 (buf0): stage tile 63 -> buf1.
  SP1();
  STAGE(1, 63);
  LDALL(0);
  MFMA_N01(); MFMA_N23();
  ILV();
  SP0(); VM0(); BAR();
  // Window 63 (buf1): compute only.
  SP1();
  LDALL(1);
  MFMA_N01(); MFMA_N23();
  SP0();

  // Epilogue: C/D mapping col=lane&15, row=(lane>>4)*4+j (m89-verified), + bias.
  const int oc0 = bcol + (wn << 6) + fr;
  const int or0 = brow + (wm << 6) + (ko << 2);
  float bv[4];
#pragma unroll
  for (int nl = 0; nl < 4; ++nl) bv[nl] = bias[oc0 + nl * 16];
#pragma unroll
  for (int ml = 0; ml < 4; ++ml)
#pragma unroll
    for (int nl = 0; nl < 4; ++nl)
#pragma unroll
      for (int j = 0; j < 4; ++j)
        out[(size_t)(or0 + ml * 16 + j) * N_DIM + (oc0 + nl * 16)] =
            acc[ml][nl][j] + bv[nl];

#undef STAGE
#undef LDALL
#undef MFMA_N01
#undef MFMA_N23
#undef BAR
#undef VM0
#undef SP1
#undef SP0
#undef SGB
#undef ILV
}

// Safety net if d_ws is too small for bf16 copies of A and W: correct but slow.
__global__ void naive_linear(const float* __restrict__ A, const float* __restrict__ W,
                             const float* __restrict__ bias, float* __restrict__ out) {
  int n = blockIdx.y;
  int o = blockIdx.x * 256 + threadIdx.x;
  const float* a = A + (size_t)n * K_DIM;
  const float* w = W + (size_t)o * K_DIM;
  float acc = 0.f;
  for (int k = 0; k < K_DIM; ++k) acc += a[k] * w[k];
  out[(size_t)n * N_DIM + o] = acc + bias[o];
}

extern "C" void kernel_launch(void* const* d_in, const int* in_sizes, int n_in,
                              void* d_out, int out_size, void* d_ws, size_t ws_size,
                              hipStream_t stream) {
  const float* A    = (const float*)d_in[0];
  const float* W    = (const float*)d_in[1];
  const float* bias = (const float*)d_in[2];
  float* out = (float*)d_out;

  const size_t a_elems = (size_t)M_DIM * K_DIM;
  const size_t w_elems = (size_t)N_DIM * K_DIM;
  const size_t need = (a_elems + w_elems) * sizeof(unsigned short);

  if (ws_size < need) {
    naive_linear<<<dim3(N_DIM / 256, M_DIM), 256, 0, stream>>>(A, W, bias, out);
    return;
  }

  unsigned short* Abf = (unsigned short*)d_ws;
  unsigned short* Wbf = Abf + a_elems;
  const int a4 = (int)(a_elems / 4), tot4 = (int)((a_elems + w_elems) / 4);
  cvt_both<<<2048, 256, 0, stream>>>(A, W, Abf, Wbf, a4, tot4);

  gemm128_2b<<<(M_DIM / 128) * (N_DIM / 128), 256, 0, stream>>>(
      (const __bf16*)Abf, (const __bf16*)Wbf, bias, out);
}

// Round 13
// 261.483 us; speedup vs baseline: 1.2048x; 1.2048x over previous
//
#include <hip/hip_runtime.h>
#include <hip/hip_bf16.h>
#include <cstdint>
#include <cstddef>

#define M_DIM 8192
#define K_DIM 4096
#define N_DIM 4096

typedef __bf16 bf16x8 __attribute__((ext_vector_type(8)));
typedef float  f32x4  __attribute__((ext_vector_type(4)));

__device__ __forceinline__ unsigned short f32_to_bf16_rne(float f) {
  unsigned int u = __builtin_bit_cast(unsigned int, f);
  u += 0x7FFFu + ((u >> 16) & 1u);
  return (unsigned short)(u >> 16);
}

// Single fused fp32->bf16 conversion for both A and W (one launch).
// Compulsory traffic 301 MB -> ~44 us measured, at the HBM roofline.
__global__ void __launch_bounds__(256) cvt_both(const float* __restrict__ A,
                                                const float* __restrict__ W,
                                                unsigned short* __restrict__ Abf,
                                                unsigned short* __restrict__ Wbf,
                                                int a4, int tot4) {
  int i = blockIdx.x * blockDim.x + threadIdx.x;
  int stride = gridDim.x * blockDim.x;
  for (; i < tot4; i += stride) {
    const float4* s = (i < a4) ? &reinterpret_cast<const float4*>(A)[i]
                               : &reinterpret_cast<const float4*>(W)[i - a4];
    ushort4* d = (i < a4) ? &reinterpret_cast<ushort4*>(Abf)[i]
                          : &reinterpret_cast<ushort4*>(Wbf)[i - a4];
    float4 v = *s;
    ushort4 o;
    o.x = f32_to_bf16_rne(v.x);
    o.y = f32_to_bf16_rne(v.y);
    o.z = f32_to_bf16_rne(v.z);
    o.w = f32_to_bf16_rne(v.w);
    *d = o;
  }
}

__device__ __forceinline__ void gload16(const void* g, void* l) {
  __builtin_amdgcn_global_load_lds((const __attribute__((address_space(1))) void*)g,
                                   (__attribute__((address_space(3))) void*)l, 16, 0, 0);
}

// 256x256-tile, BK=64, 8-wave (2Mx4N), 4-window pipelined GEMM.
// FINAL (round 13): byte-for-byte the round-7 kernel — best measured state:
// GEMM 215.8 us (1275 TF, 51% of dense peak), MfmaUtil 59.5, 0 bank
// conflicts, FETCH 197 MB, total 260.5 us. The structural alternatives were
// all measured and regressed (8-phase lockstep 244us; fusion 460us; 32x32
// shape 252us w/ conflicts; co-residency 268us w/ 3x FETCH); the register
// file bounds the design space: acc=128 AGPR caps at 2 waves/SIMD, and
// shrinking acc to co-reside forces 128^2 tiles whose FETCH blowup loses
// more than the overlap gains.
//
// Structure summary (full audits in r4-r7 history):
//  - T2 swizzle: LDS 16B-chunk (row, j) holds global k-chunk j ^ (row&7),
//    staged via pre-swizzled global source + linear gload_lds dest; ds_read
//    applies the same XOR -> 0 bank conflicts (measured).
//  - Collective read map: buf0.B last read end-W1, buf0.A end-W2, buf1.B
//    end-W3, buf1.A end-W4. Stage slots >=1 barrier after their region's
//    last collective read: W1: b1.A<-kb+1 | W2: b0.B<-kb+2 | W3: b0.A<-kb+2
//    | W4: b1.B<-kb+3. Every ds_read feeds a same-window MFMA whose counted
//    lgkm wait precedes the end barrier -> reads complete before any wave
//    crosses BAR -> stages are WAR-safe.
//  - vmcnt gates: end-W2 VM(4) -> all of buf1(kb+1) landed (oldest 12 of
//    16); end-W4 VM(4) -> all of buf0(kb+2) landed (oldest 8 of 12). Never
//    vmcnt(0) in steady state (T4).
//  - T19 sched_group_barrier interleave spreads the LDS burst across the
//    MFMA cluster; T5 setprio; T1 2D XCD grouping (FETCH 554 -> 197 MB).
__global__ void __launch_bounds__(512, 2)
gemm256_4w(const __bf16* __restrict__ A, const __bf16* __restrict__ W,
           const float* __restrict__ bias, float* __restrict__ out) {
  __shared__ __align__(16) char lds[131072];

  const int tid  = threadIdx.x;
  const int wave = tid >> 6, lane = tid & 63;
  const int wm = wave >> 2, wn = wave & 3;   // 2 x 4 wave grid, each owns 128x64
  const int fr = lane & 15, ko = lane >> 4;

  // 2D XCD grouping (bijective, 512 blocks, 8 XCDs): group g owns bm in
  // [(g&3)*8,+8), bn in [(g>>2)*8,+8); per-K-step active set ~384 KB -> L2.
  const int swzid = ((blockIdx.x & 7) << 6) + (blockIdx.x >> 3);
  const int g = swzid >> 6, w = swzid & 63;
  const int bm = ((g & 3) << 3) + (w & 7);
  const int bn = ((g >> 2) << 3) + (w >> 3);
  const int brow = bm << 8, bcol = bn << 8;

  // Staging: half-tile = 128 rows x 64 k (16 KiB), 512 threads x 2 gload16.
  const int r0 = tid >> 3;
  const int jc = (((tid & 7) ^ (r0 & 7)) << 4);
  const char* aSrc = (const char*)A + (size_t)(brow + r0) * (K_DIM * 2) + jc;
  const char* bSrc = (const char*)W + (size_t)(bcol + r0) * (K_DIM * 2) + jc;
  char* dstW = lds + (wave << 10);  // wave-uniform LDS base

#define STAGE(ms, h, bb, kt) do {                                              \
    const char* s_ = ((ms) ? bSrc : aSrc)                                      \
        + (size_t)(h) * (128ull * K_DIM * 2) + (size_t)(kt) * 128;             \
    char* d_ = dstW + (bb) * 65536 + (ms) * 32768 + (h) * 16384;               \
    gload16(s_, d_);                                                           \
    gload16(s_ + 64ull * K_DIM * 2, d_ + 8192);                                \
  } while (0)

  // Hoisted ds_read bases (row&7 == fr&7 for all fragment rows, so the
  // swizzle XOR folds into per-thread-constant low bits).
  const int low0 = (ko << 4) ^ ((fr & 7) << 4);
  const int low1 = low0 ^ 64;
  const char* baA[2][2];  // [bb][k2] -- constant-indexed only
  const char* baB[2][2];
  baA[0][0] = lds + (wm << 14) + (fr << 7) + low0;
  baA[0][1] = lds + (wm << 14) + (fr << 7) + low1;
  baA[1][0] = baA[0][0] + 65536;
  baA[1][1] = baA[0][1] + 65536;
  baB[0][0] = lds + 32768 + (wn << 13) + (fr << 7) + low0;
  baB[0][1] = lds + 32768 + (wn << 13) + (fr << 7) + low1;
  baB[1][0] = baB[0][0] + 65536;
  baB[1][1] = baB[0][1] + 65536;

  bf16x8 a[4][2];   // current m-half fragments (4 m-frags x 2 k-steps)
  bf16x8 b[4][2];   // 4 n-frags x 2 k-steps
  f32x4 acc[8][4] = {};

#define LDA8(bb, mh) do {                                                      \
    _Pragma("unroll") for (int ml = 0; ml < 4; ++ml) {                         \
      a[ml][0] = *(const bf16x8*)(baA[bb][0] + ((mh) << 13) + (ml << 11));     \
      a[ml][1] = *(const bf16x8*)(baA[bb][1] + ((mh) << 13) + (ml << 11)); }   \
  } while (0)

#define LDB4(bb, nh) do {                                                      \
    _Pragma("unroll") for (int nl = 0; nl < 2; ++nl) {                         \
      b[(nh) * 2 + nl][0] = *(const bf16x8*)(baB[bb][0] + ((nh) << 12) + (nl << 11)); \
      b[(nh) * 2 + nl][1] = *(const bf16x8*)(baB[bb][1] + ((nh) << 12) + (nl << 11)); } \
  } while (0)

#define MFMAQ(mh, nh) do {                                                     \
    _Pragma("unroll") for (int ml = 0; ml < 4; ++ml)                           \
    _Pragma("unroll") for (int nl = 0; nl < 2; ++nl)                           \
    _Pragma("unroll") for (int k2 = 0; k2 < 2; ++k2)                           \
      acc[(mh) * 4 + ml][(nh) * 2 + nl] = __builtin_amdgcn_mfma_f32_16x16x32_bf16( \
          a[ml][k2], b[(nh) * 2 + nl][k2], acc[(mh) * 4 + ml][(nh) * 2 + nl], 0, 0, 0); \
  } while (0)

#define BAR() __builtin_amdgcn_s_barrier()
#define VM(n) asm volatile("s_waitcnt vmcnt(" #n ")" ::: "memory")
#define SP1() __builtin_amdgcn_s_setprio(1)
#define SP0() __builtin_amdgcn_s_setprio(0)
#define SGB(m, n) __builtin_amdgcn_sched_group_barrier((m), (n), 0)

  // Interleave templates. Masks: MFMA=0x8, VMEM=0x10, DS_READ=0x100 (m137).
#define ILV16() do {                                                           \
    SGB(0x100, 6); SGB(0x8, 4);   /* b0,b1,a0 -> a0*b0/b1 */                   \
    SGB(0x100, 2); SGB(0x8, 4);   /* a1 -> a1*b0/b1 */                         \
    SGB(0x100, 2); SGB(0x8, 4);   /* a2 */                                     \
    SGB(0x10, 2);                                                              \
    SGB(0x100, 2); SGB(0x8, 4);   /* a3 */                                     \
    SGB(0x10, 2);                                                              \
    SGB(0x100, 2); SGB(0x8, 4);   /* b2 -> *b2 */                              \
    SGB(0x100, 2); SGB(0x8, 12);  /* b3 -> rest */                             \
  } while (0)
#define ILV8() do {                                                            \
    SGB(0x100, 2); SGB(0x8, 4);                                                \
    SGB(0x100, 2); SGB(0x8, 4);                                                \
    SGB(0x10, 2);                                                              \
    SGB(0x100, 2); SGB(0x8, 4);                                                \
    SGB(0x10, 2);                                                              \
    SGB(0x100, 2); SGB(0x8, 4);                                                \
    SGB(0x8, 16);                                                              \
  } while (0)

  // Prologue: buf0 <- k0 (all 4 halves), buf1 <- k1 (B0,B1). 12 outstanding;
  // VM(4) -> oldest 8 (= all of buf0 k0) landed. b1.A staged at iter-0 W1.
  STAGE(1, 0, 0, 0);
  STAGE(1, 1, 0, 0);
  STAGE(0, 0, 0, 0);
  STAGE(0, 1, 0, 0);
  STAGE(1, 0, 1, 1);
  STAGE(1, 1, 1, 1);
  VM(4);
  BAR();

  for (int i = 0; i < 31; ++i) {
    const int kb = 2 * i;
    // W1: Q(0,0)+Q(0,1) on buf0 | stage b1.A0,A1 <- kb+1
    SP1();
    LDB4(0, 0); LDA8(0, 0); LDB4(0, 1);
    STAGE(0, 0, 1, kb + 1); STAGE(0, 1, 1, kb + 1);
    MFMAQ(0, 0); MFMAQ(0, 1);
    ILV16();
    SP0(); BAR();
    // W2: Q(1,1)+Q(1,0) on buf0 | stage b0.B0,B1 <- kb+2 | VM(4): buf1 ready
    SP1();
    LDA8(0, 1);
    STAGE(1, 0, 0, kb + 2); STAGE(1, 1, 0, kb + 2);
    MFMAQ(1, 1); MFMAQ(1, 0);
    ILV8();
    SP0(); VM(4); BAR();
    // W3: Q(0,0)+Q(0,1) on buf1 | stage b0.A0,A1 <- kb+2
    SP1();
    LDB4(1, 0); LDA8(1, 0); LDB4(1, 1);
    STAGE(0, 0, 0, kb + 2); STAGE(0, 1, 0, kb + 2);
    MFMAQ(0, 0); MFMAQ(0, 1);
    ILV16();
    SP0(); BAR();
    // W4: Q(1,1)+Q(1,0) on buf1 | stage b1.B0,B1 <- kb+3 | VM(4): buf0 ready
    SP1();
    LDA8(1, 1);
    STAGE(1, 0, 1, kb + 3); STAGE(1, 1, 1, kb + 3);
    MFMAQ(1, 1); MFMAQ(1, 0);
    ILV8();
    SP0(); VM(4); BAR();
  }

  // Peel (kb=62): stage only b1.A <- k63 at W1; VM(0) at end-W2 drains the
  // 8 outstanding (prev-W4 b1.B: 4, W1 b1.A: 4) = all of buf1 k63.
  LDB4(0, 0); LDA8(0, 0); LDB4(0, 1);
  STAGE(0, 0, 1, 63); STAGE(0, 1, 1, 63);
  MFMAQ(0, 0); MFMAQ(0, 1); BAR();
  LDA8(0, 1);
  MFMAQ(1, 1); MFMAQ(1, 0); VM(0); BAR();
  LDB4(1, 0); LDA8(1, 0); LDB4(1, 1);
  MFMAQ(0, 0); MFMAQ(0, 1); BAR();
  LDA8(1, 1);
  MFMAQ(1, 1); MFMAQ(1, 0);

  // Epilogue: C/D mapping col=lane&15, row=(lane>>4)*4+j (m89-verified), + bias.
  const int oc0 = bcol + (wn << 6) + fr;
  const int or0 = brow + (wm << 7) + (ko << 2);
  float bv[4];
#pragma unroll
  for (int nl = 0; nl < 4; ++nl) bv[nl] = bias[oc0 + nl * 16];
#pragma unroll
  for (int ml = 0; ml < 8; ++ml)
#pragma unroll
    for (int nl = 0; nl < 4; ++nl)
#pragma unroll
      for (int j = 0; j < 4; ++j)
        out[(size_t)(or0 + ml * 16 + j) * N_DIM + (oc0 + nl * 16)] =
            acc[ml][nl][j] + bv[nl];

#undef STAGE
#undef LDA8
#undef LDB4
#undef MFMAQ
#undef BAR
#undef VM
#undef SP1
#undef SP0
#undef SGB
#undef ILV16
#undef ILV8
}

// Safety net if d_ws is too small for bf16 copies of A and W: correct but slow.
__global__ void naive_linear(const float* __restrict__ A, const float* __restrict__ W,
                             const float* __restrict__ bias, float* __restrict__ out) {
  int n = blockIdx.y;
  int o = blockIdx.x * 256 + threadIdx.x;
  const float* a = A + (size_t)n * K_DIM;
  const float* w = W + (size_t)o * K_DIM;
  float acc = 0.f;
  for (int k = 0; k < K_DIM; ++k) acc += a[k] * w[k];
  out[(size_t)n * N_DIM + o] = acc + bias[o];
}

extern "C" void kernel_launch(void* const* d_in, const int* in_sizes, int n_in,
                              void* d_out, int out_size, void* d_ws, size_t ws_size,
                              hipStream_t stream) {
  const float* A    = (const float*)d_in[0];
  const float* W    = (const float*)d_in[1];
  const float* bias = (const float*)d_in[2];
  float* out = (float*)d_out;

  const size_t a_elems = (size_t)M_DIM * K_DIM;
  const size_t w_elems = (size_t)N_DIM * K_DIM;
  const size_t need = (a_elems + w_elems) * sizeof(unsigned short);

  if (ws_size < need) {
    naive_linear<<<dim3(N_DIM / 256, M_DIM), 256, 0, stream>>>(A, W, bias, out);
    return;
  }

  unsigned short* Abf = (unsigned short*)d_ws;
  unsigned short* Wbf = Abf + a_elems;
  const int a4 = (int)(a_elems / 4), tot4 = (int)((a_elems + w_elems) / 4);
  cvt_both<<<2048, 256, 0, stream>>>(A, W, Abf, Wbf, a4, tot4);

  gemm256_4w<<<(M_DIM / 256) * (N_DIM / 256), 512, 0, stream>>>(
      (const __bf16*)Abf, (const __bf16*)Wbf, bias, out);
}